// Round 4
// baseline (120.862 us; speedup 1.0000x reference)
//
#include <hip/hip_runtime.h>
#include <stdint.h>

// Problem dims (fixed by reference): E=16, B=8, S=2048, D=2048
#define N_TOK   16384          // B*S
#define D_MODEL 2048
#define N_EXP   16
#define CAP     1024           // N_TOK / N_EXP
#define TOTAL   (N_TOK * D_MODEL)        // 33,554,432 elements
#define NVEC    (TOTAL / 4)              // 8,388,608 float4 groups

// keep  <=>  u < 0.9f  <=>  (bits >> 9) < 7549747 (0.9f == 7549747*2^-23 exactly)
#define KEEP_THR 0x733333u

// ---------------------------------------------------------------------------
// Threefry-2x32, 20 rounds, key = (0, 42) == jax.random.key(42).
// Partitionable path, 32-bit draws: counter = (hi,lo) = (0, i) and the
// sub-64-bit narrowing XOR-FOLDS the two output words:
//     bits[i] = x0 ^ x1   (jax prng.py: `bits1 ^ bits2` for bit_width < 64)
// ---------------------------------------------------------------------------
__device__ __forceinline__ uint32_t tf_bits(uint32_t i) {
    const uint32_t k0 = 0u;
    const uint32_t k1 = 42u;
    const uint32_t k2 = 0x1BD11BDAu ^ 0u ^ 42u;
    uint32_t x0 = 0u + k0;        // counter hi = 0
    uint32_t x1 = i + k1;         // counter lo = i
#define TF_R(r) { x0 += x1; x1 = (x1 << (r)) | (x1 >> (32 - (r))); x1 ^= x0; }
    TF_R(13) TF_R(15) TF_R(26) TF_R(6)
    x0 += k1; x1 += k2 + 1u;
    TF_R(17) TF_R(29) TF_R(16) TF_R(24)
    x0 += k2; x1 += k0 + 2u;
    TF_R(13) TF_R(15) TF_R(26) TF_R(6)
    x0 += k0; x1 += k1 + 3u;
    TF_R(17) TF_R(29) TF_R(16) TF_R(24)
    x0 += k1; x1 += k2 + 4u;
    TF_R(13) TF_R(15) TF_R(26) TF_R(6)
    x0 += k2; x1 += k0 + 5u;
#undef TF_R
    return x0 ^ x1;               // XOR-fold (partitionable sub-64 narrowing)
}

// ---------------------------------------------------------------------------
// Kernel 1: within-expert rank. One block (1 wave) per expert; int4 route
// loads (256 tokens/iter) + wave shuffle-scan of per-lane match counts.
// srcrow[t] = routes[t]*CAP + rank(t)
// ---------------------------------------------------------------------------
__global__ __launch_bounds__(64) void rank_kernel(const int* __restrict__ routes,
                                                  int* __restrict__ srcrow) {
    const int e    = blockIdx.x;     // expert id
    const int lane = threadIdx.x;    // 0..63
    const int4* routes4 = (const int4*)routes;
    int running = 0;
    for (int base = 0; base < N_TOK / 4; base += 64) {
        int4 r = routes4[base + lane];
        int m0 = (r.x == e), m1 = (r.y == e), m2 = (r.z == e), m3 = (r.w == e);
        int cnt = m0 + m1 + m2 + m3;
        // inclusive wave prefix sum of cnt
        int pre = cnt;
        #pragma unroll
        for (int dlt = 1; dlt < 64; dlt <<= 1) {
            int up = __shfl_up(pre, dlt);
            if (lane >= dlt) pre += up;
        }
        int excl = pre - cnt;                 // matches in earlier lanes
        int tot  = __shfl(pre, 63);           // matches in whole chunk
        int t0 = (base + lane) * 4;
        int p = running + excl;
        if (m0) { srcrow[t0 + 0] = e * CAP + p; p++; }
        if (m1) { srcrow[t0 + 1] = e * CAP + p; p++; }
        if (m2) { srcrow[t0 + 2] = e * CAP + p; p++; }
        if (m3) { srcrow[t0 + 3] = e * CAP + p; p++; }
        running += tot;
    }
}

// ---------------------------------------------------------------------------
// Kernel 2: combine + dropout + residual. One float4 group (4 consecutive
// elements, same token) per thread; one full threefry per element.
// ---------------------------------------------------------------------------
__global__ __launch_bounds__(256) void combine_kernel(
        const float4* __restrict__ hidden,
        const float*  __restrict__ eo,
        const int*    __restrict__ srcrow,
        const float*  __restrict__ rpm,
        float4*       __restrict__ out) {
    const int g = blockIdx.x * 256 + threadIdx.x;   // [0, NVEC)
    const int j = g << 2;                           // element index

    const uint32_t m0 = tf_bits((uint32_t)(j + 0)) >> 9;
    const uint32_t m1 = tf_bits((uint32_t)(j + 1)) >> 9;
    const uint32_t m2 = tf_bits((uint32_t)(j + 2)) >> 9;
    const uint32_t m3 = tf_bits((uint32_t)(j + 3)) >> 9;

    const int t = j >> 11;               // token (D=2048; 4 | 2048 so uniform)
    const int d = j & 2047;

    const float s = rpm[t] * (1.0f / 0.9f);
    const int   r = srcrow[t];

    const float4 h = hidden[g];
    const float4 e = *(const float4*)(eo + (size_t)r * D_MODEL + d);

    float4 o;
    o.x = h.x + ((m0 < KEEP_THR) ? e.x * s : 0.0f);
    o.y = h.y + ((m1 < KEEP_THR) ? e.y * s : 0.0f);
    o.z = h.z + ((m2 < KEEP_THR) ? e.z * s : 0.0f);
    o.w = h.w + ((m3 < KEEP_THR) ? e.w * s : 0.0f);

    out[g] = o;
}

// ---------------------------------------------------------------------------
extern "C" void kernel_launch(void* const* d_in, const int* in_sizes, int n_in,
                              void* d_out, int out_size, void* d_ws, size_t ws_size,
                              hipStream_t stream) {
    const float* hidden = (const float*)d_in[0];   // [B,S,D] f32
    const float* eo     = (const float*)d_in[1];   // [E,CAP,D] f32
    const int*   routes = (const int*)d_in[2];     // [N] i32
    const float* rpm    = (const float*)d_in[3];   // [N] f32

    int* srcrow = (int*)d_ws;                      // N_TOK ints = 64 KB scratch

    rank_kernel<<<N_EXP, 64, 0, stream>>>(routes, srcrow);
    combine_kernel<<<NVEC / 256, 256, 0, stream>>>(
        (const float4*)hidden, eo, srcrow, rpm, (float4*)d_out);
}